// Round 1
// baseline (1612.554 us; speedup 1.0000x reference)
//
#include <hip/hip_runtime.h>
#include <hip/hip_bf16.h>
#include <stdint.h>

// Int8SymmetricLinear: out[m,n] = sum_k x[m,k] * (int8 W[n,k]) * scale[n] + bias[n]
// M=8192 (B*S), K=4096, N=11008.  Strategy: cast x->bf16 (RTNE) and W->bf16
// (exact: |W|<=127 < 256) in a prepass, then m97-style bf16 MFMA GEMM
// (128x128 tile, BK=32, global_load_lds width 16). Scale+bias in fp32 epilogue.

#define M_DIM 8192
#define K_DIM 4096
#define N_DIM 11008
#define BM 128
#define BN 128
#define BK 32

typedef __attribute__((ext_vector_type(8))) short short8;   // 8 bf16 = 4 VGPRs
typedef __attribute__((ext_vector_type(4))) float floatx4;

__device__ __forceinline__ unsigned short f2bf(float f) {
    __hip_bfloat16 h = __float2bfloat16(f);   // RTNE
    return __builtin_bit_cast(unsigned short, h);
}

// ---- prepass: x fp32 -> bf16 bits (8 elems/thread) ----
__global__ void cvt_x(const float* __restrict__ x, unsigned short* __restrict__ o) {
    int i = (blockIdx.x * 256 + threadIdx.x) * 8;
    float4 a = *(const float4*)(x + i);
    float4 b = *(const float4*)(x + i + 4);
    union { unsigned short h[8]; uint4 v; } u;
    u.h[0] = f2bf(a.x); u.h[1] = f2bf(a.y); u.h[2] = f2bf(a.z); u.h[3] = f2bf(a.w);
    u.h[4] = f2bf(b.x); u.h[5] = f2bf(b.y); u.h[6] = f2bf(b.z); u.h[7] = f2bf(b.w);
    *(uint4*)(o + i) = u.v;
}

// ---- prepass: W int32 (values in [-127,127]) -> bf16 bits (exact) ----
__global__ void cvt_w(const int* __restrict__ w, unsigned short* __restrict__ o) {
    int i = (blockIdx.x * 256 + threadIdx.x) * 8;
    int4 a = *(const int4*)(w + i);
    int4 b = *(const int4*)(w + i + 4);
    union { unsigned short h[8]; uint4 v; } u;
    u.h[0] = f2bf((float)a.x); u.h[1] = f2bf((float)a.y);
    u.h[2] = f2bf((float)a.z); u.h[3] = f2bf((float)a.w);
    u.h[4] = f2bf((float)b.x); u.h[5] = f2bf((float)b.y);
    u.h[6] = f2bf((float)b.z); u.h[7] = f2bf((float)b.w);
    *(uint4*)(o + i) = u.v;
}

// ---- main GEMM: C = A(MxK) * B(NxK)^T, both bf16, + scale/bias epilogue ----
__global__ __launch_bounds__(256) void gemm_bf16(
    const unsigned short* __restrict__ A,
    const unsigned short* __restrict__ B,
    const float* __restrict__ scale,
    const float* __restrict__ bias,
    float* __restrict__ C) {
    __shared__ unsigned short As[BM * BK];   // 8 KiB, row-major, 64B/row
    __shared__ unsigned short Bs[BN * BK];

    const int tid  = threadIdx.x;
    const int lane = tid & 63;
    const int wave = tid >> 6;
    const int wm = wave & 1;        // 2x2 wave grid, each wave owns 64x64
    const int wn = wave >> 1;
    const int bm = blockIdx.x;
    const int bn = blockIdx.y;

    floatx4 acc[4][4] = {};

    const unsigned short* a_src = A + (size_t)bm * BM * K_DIM;
    const unsigned short* b_src = B + (size_t)bn * BN * K_DIM;

    const int fr = lane & 15;           // fragment row within 16x16
    const int fk = (lane >> 4) * 8;     // fragment k offset

    for (int k0 = 0; k0 < K_DIM; k0 += BK) {
        // stage A tile: 128x32 bf16 = 8192B = 2 issues of 256 lanes x 16B
#pragma unroll
        for (int iss = 0; iss < 2; ++iss) {
            int li = iss * 256 + tid;
            int row = li >> 2, ch = (li & 3) * 8;
            __builtin_amdgcn_global_load_lds(
                (const __attribute__((address_space(1))) void*)(a_src + (size_t)row * K_DIM + k0 + ch),
                (__attribute__((address_space(3))) void*)(As + li * 8), 16, 0, 0);
        }
#pragma unroll
        for (int iss = 0; iss < 2; ++iss) {
            int li = iss * 256 + tid;
            int row = li >> 2, ch = (li & 3) * 8;
            __builtin_amdgcn_global_load_lds(
                (const __attribute__((address_space(1))) void*)(b_src + (size_t)row * K_DIM + k0 + ch),
                (__attribute__((address_space(3))) void*)(Bs + li * 8), 16, 0, 0);
        }
        __syncthreads();

        short8 af[4], bf[4];
#pragma unroll
        for (int i = 0; i < 4; ++i)
            af[i] = *(const short8*)(As + (wm * 64 + i * 16 + fr) * BK + fk);
#pragma unroll
        for (int i = 0; i < 4; ++i)
            bf[i] = *(const short8*)(Bs + (wn * 64 + i * 16 + fr) * BK + fk);
#pragma unroll
        for (int mi = 0; mi < 4; ++mi)
#pragma unroll
            for (int ni = 0; ni < 4; ++ni)
                acc[mi][ni] = __builtin_amdgcn_mfma_f32_16x16x32_bf16(
                    af[mi], bf[ni], acc[mi][ni], 0, 0, 0);
        __syncthreads();
    }

    // epilogue: C/D layout col=lane&15, row=(lane>>4)*4+r
    const int cm = (lane >> 4) * 4;
    const int cn = lane & 15;
#pragma unroll
    for (int ni = 0; ni < 4; ++ni) {
        int gn = bn * BN + wn * 64 + ni * 16 + cn;
        float s = scale[gn], bb = bias[gn];
#pragma unroll
        for (int mi = 0; mi < 4; ++mi) {
            int gm0 = bm * BM + wm * 64 + mi * 16 + cm;
#pragma unroll
            for (int r = 0; r < 4; ++r)
                C[(size_t)(gm0 + r) * N_DIM + gn] = acc[mi][ni][r] * s + bb;
        }
    }
}

// ---- fallback (ws too small): same tile, register staging + on-the-fly cast ----
__global__ __launch_bounds__(256) void gemm_fused(
    const float* __restrict__ X, const int* __restrict__ W,
    const float* __restrict__ scale, const float* __restrict__ bias,
    float* __restrict__ C) {
    __shared__ unsigned short As[BM * BK];
    __shared__ unsigned short Bs[BN * BK];
    const int tid = threadIdx.x;
    const int lane = tid & 63, wave = tid >> 6;
    const int wm = wave & 1, wn = wave >> 1;
    const int bm = blockIdx.x, bn = blockIdx.y;
    floatx4 acc[4][4] = {};
    const int srow = tid >> 1;
    const int scol = (tid & 1) * 16;
    const float* xp = X + (size_t)(bm * BM + srow) * K_DIM + scol;
    const int*   wp = W + (size_t)(bn * BN + srow) * K_DIM + scol;
    const int fr = lane & 15, fk = (lane >> 4) * 8;

    for (int k0 = 0; k0 < K_DIM; k0 += BK) {
        union { float4 v[4]; float f[16]; } fx;
        union { int4 v[4]; int s[16]; } fw;
#pragma unroll
        for (int i = 0; i < 4; ++i) fx.v[i] = *(const float4*)(xp + k0 + i * 4);
#pragma unroll
        for (int i = 0; i < 4; ++i) fw.v[i] = *(const int4*)(wp + k0 + i * 4);
        union { unsigned short h[16]; uint4 v[2]; } ha, hb;
#pragma unroll
        for (int i = 0; i < 16; ++i) ha.h[i] = f2bf(fx.f[i]);
#pragma unroll
        for (int i = 0; i < 16; ++i) hb.h[i] = f2bf((float)fw.s[i]);
        __syncthreads();   // previous iteration's frag reads done
        *(uint4*)(As + srow * BK + scol)     = ha.v[0];
        *(uint4*)(As + srow * BK + scol + 8) = ha.v[1];
        *(uint4*)(Bs + srow * BK + scol)     = hb.v[0];
        *(uint4*)(Bs + srow * BK + scol + 8) = hb.v[1];
        __syncthreads();

        short8 af[4], bf[4];
#pragma unroll
        for (int i = 0; i < 4; ++i)
            af[i] = *(const short8*)(As + (wm * 64 + i * 16 + fr) * BK + fk);
#pragma unroll
        for (int i = 0; i < 4; ++i)
            bf[i] = *(const short8*)(Bs + (wn * 64 + i * 16 + fr) * BK + fk);
#pragma unroll
        for (int mi = 0; mi < 4; ++mi)
#pragma unroll
            for (int ni = 0; ni < 4; ++ni)
                acc[mi][ni] = __builtin_amdgcn_mfma_f32_16x16x32_bf16(
                    af[mi], bf[ni], acc[mi][ni], 0, 0, 0);
    }

    const int cm = (lane >> 4) * 4;
    const int cn = lane & 15;
#pragma unroll
    for (int ni = 0; ni < 4; ++ni) {
        int gn = bn * BN + wn * 64 + ni * 16 + cn;
        float s = scale[gn], bb = bias[gn];
#pragma unroll
        for (int mi = 0; mi < 4; ++mi) {
            int gm0 = bm * BM + wm * 64 + mi * 16 + cm;
#pragma unroll
            for (int r = 0; r < 4; ++r)
                C[(size_t)(gm0 + r) * N_DIM + gn] = acc[mi][ni][r] * s + bb;
        }
    }
}

extern "C" void kernel_launch(void* const* d_in, const int* in_sizes, int n_in,
                              void* d_out, int out_size, void* d_ws, size_t ws_size,
                              hipStream_t stream) {
    const float* x     = (const float*)d_in[0];
    const int*   w     = (const int*)d_in[1];     // int inputs delivered as int32
    const float* scale = (const float*)d_in[2];
    const float* bias  = (const float*)d_in[3];
    float* out = (float*)d_out;

    const size_t a_elems = (size_t)M_DIM * K_DIM;   // 33,554,432
    const size_t b_elems = (size_t)N_DIM * K_DIM;   // 45,088,768
    const size_t need = (a_elems + b_elems) * sizeof(unsigned short);  // ~150 MiB

    dim3 grid(M_DIM / BM, N_DIM / BN);   // 64 x 86

    if (ws_size >= need) {
        unsigned short* xa = (unsigned short*)d_ws;
        unsigned short* wb = xa + a_elems;
        cvt_x<<<(int)(a_elems / 2048), 256, 0, stream>>>(x, xa);
        cvt_w<<<(int)(b_elems / 2048), 256, 0, stream>>>(w, wb);
        gemm_bf16<<<grid, 256, 0, stream>>>(xa, wb, scale, bias, out);
    } else {
        gemm_fused<<<grid, 256, 0, stream>>>(x, w, scale, bias, out);
    }
}